// Round 1
// baseline (401.160 us; speedup 1.0000x reference)
//
#include <hip/hip_runtime.h>
#include <cstdint>
#include <cstddef>

// ---------------------------------------------------------------------------
// DetCenterDense: fused conv3x3(128->64)+ReLU -> 4x conv1x1 heads (20 ch total,
// sigmoid on last 4) over [4,128,512,512] fp32, NCHW. bf16 MFMA implicit GEMM.
// ---------------------------------------------------------------------------

typedef __bf16 bf16x8 __attribute__((ext_vector_type(8)));
typedef float f32x16 __attribute__((ext_vector_type(16)));

__device__ __forceinline__ unsigned short f2bf(float x) {
    union { float f; unsigned int u; } v; v.f = x;
    unsigned int u = v.u;
    // round-to-nearest-even bf16
    unsigned int r = (u + 0x7FFFu + ((u >> 16) & 1u)) >> 16;
    return (unsigned short)r;
}
__device__ __forceinline__ unsigned int pack2(float a, float b) {
    return (unsigned int)f2bf(a) | ((unsigned int)f2bf(b) << 16);
}

// ---------------------------------------------------------------------------
// Prepass: repack w_shared [64][128][3][3] fp32 -> bf16 fragment-ordered buffer
// ws2 layout: [kstep kappa(72)][hw(2)][och(64)][8 bf16]
//   kappa = (cin>>5)*18 + tap*2 + ((cin>>4)&1) ;  hw = (cin>>3)&1 ; j = cin&7
// so a wave's B-fragment (lane: och = nt*32 + (l&31), hw = l>>5) is one
// contiguous dwordx4 per lane, coalesced across lanes.
// ---------------------------------------------------------------------------
__global__ void prep_w_kernel(const float* __restrict__ w, unsigned short* __restrict__ ws2) {
    int idx = blockIdx.x * 256 + threadIdx.x;
    if (idx >= 64 * 128 * 9) return;
    int tap = idx % 9;
    int cin = (idx / 9) % 128;
    int och = idx / (9 * 128);
    int chunk = cin >> 5;
    int c32 = cin & 31;
    int ks = (c32 >> 4) & 1;
    int hw = (c32 >> 3) & 1;
    int j  = c32 & 7;
    int kappa = chunk * 18 + tap * 2 + ks;
    int dst = ((kappa * 2 + hw) * 64 + och) * 8 + j;
    ws2[dst] = f2bf(w[idx]);
}

// ---------------------------------------------------------------------------
// Main fused kernel.
// Grid: (W/128=4, H/2=256, B=4). Block: 256 threads = 4 waves.
// Block tile: 2 rows x 128 cols. Wave tile: 64 px x 64 ch (2x2 mfma 32x32x16).
// ---------------------------------------------------------------------------
__global__ __launch_bounds__(256, 2)
void det_main_kernel(const float* __restrict__ feature,
                     const unsigned short* __restrict__ ws2,
                     const float* __restrict__ w_cls, const float* __restrict__ b_cls,
                     const float* __restrict__ w_box, const float* __restrict__ b_box,
                     const float* __restrict__ w_dir, const float* __restrict__ b_dir,
                     const float* __restrict__ w_scr, const float* __restrict__ b_scr,
                     float* __restrict__ out) {
    // F: [4 rows][132 w][32 cin] bf16 (group-swizzled). Reused as X [256 px][64 ch].
    __shared__ __align__(16) unsigned short s_f[4 * 132 * 32];
    __shared__ __align__(16) unsigned short s_wc[32 * 64];   // 1x1 weights, och-padded to 32
    __shared__ float s_bias[32];

    const int tid  = threadIdx.x;
    const int lane = tid & 63;
    const int wave = tid >> 6;
    const int l31  = lane & 31;
    const int hw   = lane >> 5;        // k-group half
    const int wrow = wave >> 1;        // 0..1: output row within block
    const int wcb  = (wave & 1) * 64;  // col base within block
    const int bz = blockIdx.z;
    const int h0 = blockIdx.y * 2;
    const int w0 = blockIdx.x * 128;
    const size_t CH = 512 * 512;

    // ---- stage 1x1-head weights (bf16, row-swizzled) + bias into LDS ----
    {
        int och = tid >> 3;
        int j8  = (tid & 7) * 8;
        float v[8];
        if (och < 20) {
            const float* src = (och < 2)  ? (w_cls + och * 64)
                             : (och < 8)  ? (w_box + (och - 2) * 64)
                             : (och < 16) ? (w_dir + (och - 8) * 64)
                                          : (w_scr + (och - 16) * 64);
            #pragma unroll
            for (int j = 0; j < 8; ++j) v[j] = src[j8 + j];
        } else {
            #pragma unroll
            for (int j = 0; j < 8; ++j) v[j] = 0.f;
        }
        uint4 u = make_uint4(pack2(v[0], v[1]), pack2(v[2], v[3]),
                             pack2(v[4], v[5]), pack2(v[6], v[7]));
        int off = och * 128 + ((j8 * 2) ^ ((och & 7) << 4));
        *(uint4*)((char*)s_wc + off) = u;
        if (tid < 32) {
            s_bias[tid] = (tid < 2)  ? b_cls[tid]
                        : (tid < 8)  ? b_box[tid - 2]
                        : (tid < 16) ? b_dir[tid - 8]
                        : (tid < 20) ? b_scr[tid - 16] : 0.f;
        }
    }

    f32x16 zero16;
    #pragma unroll
    for (int e = 0; e < 16; ++e) zero16[e] = 0.f;

    f32x16 acc[2][2];
    acc[0][0] = zero16; acc[0][1] = zero16; acc[1][0] = zero16; acc[1][1] = zero16;

    // ---- K loop: 4 cin-chunks x 9 taps x 2 ksteps of 16 ----
    for (int chunk = 0; chunk < 4; ++chunk) {
        __syncthreads();
        // stage feature chunk: rows h0-1..h0+2, cols w0-1..w0+128, cin chunk of 32
        for (int it = 0; it < 9; ++it) {
            int gid = it * 256 + tid;
            if (gid >= 2112) break;           // 4 c8 * 4 rows * 132 w-slots
            int c8  = gid / 528;              // cin octet 0..3
            int rem = gid - c8 * 528;
            int r   = rem / 132;              // staged row 0..3
            int w   = rem - r * 132;          // staged col slot
            if (w < 130) {
                int h  = h0 - 1 + r;
                int wg = w0 - 1 + w;
                bool ok = (h >= 0) & (h < 512) & (wg >= 0) & (wg < 512);
                const float* sp = feature
                    + (size_t)(bz * 128 + chunk * 32 + c8 * 8) * CH
                    + (size_t)h * 512 + wg;
                float v[8];
                #pragma unroll
                for (int j = 0; j < 8; ++j) v[j] = ok ? sp[(size_t)j * CH] : 0.f;
                uint4 u = make_uint4(pack2(v[0], v[1]), pack2(v[2], v[3]),
                                     pack2(v[4], v[5]), pack2(v[6], v[7]));
                int off = ((r * 132 + w) * 32 + ((c8 ^ ((w >> 2) & 3)) * 8)) * 2;
                *(uint4*)((char*)s_f + off) = u;
            }
        }
        __syncthreads();

        #pragma unroll
        for (int tap = 0; tap < 9; ++tap) {
            const int kh = tap / 3, kw = tap % 3;
            bf16x8 B[2][2];   // [ks][nt] weights from global (L2-resident)
            #pragma unroll
            for (int ks = 0; ks < 2; ++ks) {
                #pragma unroll
                for (int nt = 0; nt < 2; ++nt) {
                    size_t bi = ((size_t)(((chunk * 18 + tap * 2 + ks) * 2 + hw) * 64
                                          + nt * 32 + l31)) * 8;
                    B[ks][nt] = *(const bf16x8*)(ws2 + bi);
                }
            }
            bf16x8 A[2][2];   // [mt][ks] feature patches from LDS
            #pragma unroll
            for (int mt = 0; mt < 2; ++mt) {
                #pragma unroll
                for (int ks = 0; ks < 2; ++ks) {
                    int fw  = wcb + mt * 32 + l31 + kw;
                    int grp = (ks * 2 + hw) ^ ((fw >> 2) & 3);
                    int off = (((wrow + kh) * 132 + fw) * 32 + grp * 8) * 2;
                    A[mt][ks] = *(const bf16x8*)((const char*)s_f + off);
                }
            }
            #pragma unroll
            for (int mt = 0; mt < 2; ++mt) {
                #pragma unroll
                for (int nt = 0; nt < 2; ++nt) {
                    acc[mt][nt] = __builtin_amdgcn_mfma_f32_32x32x16_bf16(
                        A[mt][0], B[0][nt], acc[mt][nt], 0, 0, 0);
                    acc[mt][nt] = __builtin_amdgcn_mfma_f32_32x32x16_bf16(
                        A[mt][1], B[1][nt], acc[mt][nt], 0, 0, 0);
                }
            }
        }
    }

    // ---- ReLU -> bf16 X tile in LDS (reuse F region), row-XOR swizzled ----
    __syncthreads();   // all waves done reading s_f
    unsigned short* X = s_f;
    #pragma unroll
    for (int mt = 0; mt < 2; ++mt) {
        #pragma unroll
        for (int nt = 0; nt < 2; ++nt) {
            #pragma unroll
            for (int r = 0; r < 16; ++r) {
                float v = fmaxf(acc[mt][nt][r], 0.f);
                int mrow = (r & 3) + 8 * (r >> 2) + 4 * hw;
                int pxb  = wave * 64 + mt * 32 + mrow;
                int ch   = nt * 32 + l31;
                int off  = pxb * 128 + ((ch * 2) ^ ((pxb & 7) << 4));
                *(unsigned short*)((char*)X + off) = f2bf(v);
            }
        }
    }
    // wave-local: compiler orders ds_write -> ds_read with lgkmcnt

    // ---- stage 2: out[och(20->32)][px] = Wc @ X, K=64 ----
    f32x16 acc2[2];
    acc2[0] = zero16; acc2[1] = zero16;
    #pragma unroll
    for (int ks = 0; ks < 4; ++ks) {
        int ch0 = ks * 16 + hw * 8;
        int offA = l31 * 128 + ((ch0 * 2) ^ ((l31 & 7) << 4));
        bf16x8 a2 = *(const bf16x8*)((const char*)s_wc + offA);
        #pragma unroll
        for (int nt = 0; nt < 2; ++nt) {
            int pxb  = wave * 64 + nt * 32 + l31;
            int offB = pxb * 128 + ((ch0 * 2) ^ ((pxb & 7) << 4));
            bf16x8 b2 = *(const bf16x8*)((const char*)X + offB);
            acc2[nt] = __builtin_amdgcn_mfma_f32_32x32x16_bf16(a2, b2, acc2[nt], 0, 0, 0);
        }
    }

    // ---- epilogue: bias, sigmoid on och 16..19, coalesced stores ----
    const int h = h0 + wrow;
    #pragma unroll
    for (int nt = 0; nt < 2; ++nt) {
        int wg = w0 + wcb + nt * 32 + l31;
        #pragma unroll
        for (int r = 0; r < 16; ++r) {
            int och = (r & 3) + 8 * (r >> 2) + 4 * hw;
            if (och < 20) {
                float v = acc2[nt][r] + s_bias[och];
                if (och >= 16) v = 1.f / (1.f + __expf(-v));
                out[(((size_t)bz * 20 + och) * 512 + h) * 512 + wg] = v;
            }
        }
    }
}

extern "C" void kernel_launch(void* const* d_in, const int* in_sizes, int n_in,
                              void* d_out, int out_size, void* d_ws, size_t ws_size,
                              hipStream_t stream) {
    const float* feature  = (const float*)d_in[0];
    const float* w_shared = (const float*)d_in[1];
    const float* w_cls = (const float*)d_in[2];
    const float* b_cls = (const float*)d_in[3];
    const float* w_box = (const float*)d_in[4];
    const float* b_box = (const float*)d_in[5];
    const float* w_dir = (const float*)d_in[6];
    const float* b_dir = (const float*)d_in[7];
    const float* w_scr = (const float*)d_in[8];
    const float* b_scr = (const float*)d_in[9];
    float* out = (float*)d_out;
    unsigned short* ws2 = (unsigned short*)d_ws;   // 64*1152 bf16 = 147456 B

    prep_w_kernel<<<288, 256, 0, stream>>>(w_shared, ws2);

    dim3 grid(4, 256, 4);   // (W/128, H/2, B)
    det_main_kernel<<<grid, 256, 0, stream>>>(feature, ws2,
                                              w_cls, b_cls, w_box, b_box,
                                              w_dir, b_dir, w_scr, b_scr, out);
}